// Round 3
// baseline (184.793 us; speedup 1.0000x reference)
//
#include <hip/hip_runtime.h>

// Fused NCA step, 4 px/thread walking R=4 rows with register row-rotation.
// perchannel 3x3 (identity/sobelx/sobely/lap, circular pad) -> 1x1(16->6)+relu
// -> tanh(6->4), sigmoid(6->4) -> gated blend. x: [16,4,512,512] f32.
// Row rotation: after warmup each step loads only ONE new row per channel
// (4.5 load-instr/site vs 9 in the non-walking version).

constexpr int Bn = 16, Cn = 4, Hn = 512, Wn = 512, HID = 6, R = 4;

__device__ __forceinline__ float frcp(float v) { return __builtin_amdgcn_rcpf(v); }

__global__ __launch_bounds__(256) void nca_strip(
    const float* __restrict__ x,
    const float* __restrict__ w1w, const float* __restrict__ w1b,
    const float* __restrict__ w2w, const float* __restrict__ w2b,
    const float* __restrict__ w3w, const float* __restrict__ w3b,
    float* __restrict__ out)
{
    const int S = Hn / R;                        // 128 strips
    int tid = blockIdx.x * 256 + threadIdx.x;
    int g = tid & 127;                           // 4-px quad; wave = 256 contiguous px
    int s = (tid >> 7) & (S - 1);
    int b = tid >> 14;

    int w0 = g << 2;
    int wl = (w0 == 0)      ? Wn - 1 : w0 - 1;   // circular pad in w
    int wr = (w0 + 4 == Wn) ? 0      : w0 + 4;
    int h0 = s * R;
    int hm = (h0 == 0) ? Hn - 1 : h0 - 1;        // circular pad in h

    const size_t plane = (size_t)Hn * Wn;
    const float* xb = x + (size_t)b * Cn * plane;

    // rolling rows: t = row h-1, m = row h, per channel, 6 columns (1 halo each side)
    float t[Cn][6], m[Cn][6];
    #pragma unroll
    for (int c = 0; c < Cn; ++c) {
        const float* xp = xb + c * plane;
        const float* rt = xp + (size_t)hm * Wn;
        const float* rm = xp + (size_t)h0 * Wn;
        float4 t4 = *(const float4*)(rt + w0);
        float4 m4 = *(const float4*)(rm + w0);
        t[c][0] = rt[wl]; t[c][1] = t4.x; t[c][2] = t4.y; t[c][3] = t4.z; t[c][4] = t4.w; t[c][5] = rt[wr];
        m[c][0] = rm[wl]; m[c][1] = m4.x; m[c][2] = m4.y; m[c][3] = m4.z; m[c][4] = m4.w; m[c][5] = rm[wr];
    }

    #pragma unroll
    for (int r = 0; r < R; ++r) {
        int h  = h0 + r;
        int hb = (h + 1) & (Hn - 1);             // wrap at bottom

        float bot[Cn][6];
        #pragma unroll
        for (int c = 0; c < Cn; ++c) {
            const float* rp = xb + c * plane + (size_t)hb * Wn;
            float4 b4 = *(const float4*)(rp + w0);
            bot[c][0] = rp[wl]; bot[c][1] = b4.x; bot[c][2] = b4.y; bot[c][3] = b4.z; bot[c][4] = b4.w; bot[c][5] = rp[wr];
        }

        float acc[HID][4];
        #pragma unroll
        for (int o = 0; o < HID; ++o) {
            float bv = w1b[o];
            #pragma unroll
            for (int i = 0; i < 4; ++i) acc[o][i] = bv;
        }

        #pragma unroll
        for (int c = 0; c < Cn; ++c) {
            // column-separable: sc = t+2m+b ([1,2,1] vert), dc = b-t ([-1,0,1] vert)
            float sc[6], dc[6];
            #pragma unroll
            for (int j = 0; j < 6; ++j) {
                sc[j] = fmaf(2.f, m[c][j], t[c][j] + bot[c][j]);
                dc[j] = bot[c][j] - t[c][j];
            }
            #pragma unroll
            for (int i = 0; i < 4; ++i) {
                int j = i + 1;
                float mc = m[c][j];
                float y1 = sc[j + 1] - sc[j - 1];                      // sobel_x
                float y2 = fmaf(2.f, dc[j], dc[j - 1] + dc[j + 1]);    // sobel_y
                float y3 = fmaf(-16.f, mc,
                           fmaf(2.f, sc[j], sc[j - 1] + sc[j + 1]));   // laplacian
                #pragma unroll
                for (int o = 0; o < HID; ++o) {
                    acc[o][i] = fmaf(w1w[o*16 + c*4 + 0], mc,
                                fmaf(w1w[o*16 + c*4 + 1], y1,
                                fmaf(w1w[o*16 + c*4 + 2], y2,
                                fmaf(w1w[o*16 + c*4 + 3], y3, acc[o][i]))));
                }
            }
        }

        #pragma unroll
        for (int o = 0; o < HID; ++o)
            #pragma unroll
            for (int i = 0; i < 4; ++i)
                acc[o][i] = fmaxf(acc[o][i], 0.f);   // relu

        float* ob = out + (size_t)b * Cn * plane + (size_t)h * Wn + w0;
        #pragma unroll
        for (int j = 0; j < Cn; ++j) {
            float res[4];
            #pragma unroll
            for (int i = 0; i < 4; ++i) {
                float u = w2b[j], gg = w3b[j];
                #pragma unroll
                for (int o = 0; o < HID; ++o) {
                    u  = fmaf(w2w[j*HID + o], acc[o][i], u);
                    gg = fmaf(w3w[j*HID + o], acc[o][i], gg);
                }
                // tanh(u) = 1 - 2/(exp(2u)+1); sigmoid(g) = 1/(1+exp(-g))
                float th = 1.f - 2.f * frcp(__expf(2.f * u) + 1.f);
                float sg = frcp(1.f + __expf(-gg));
                res[i] = fmaf(sg, m[j][i + 1] - th, th);   // x center = m row
            }
            *(float4*)(ob + (size_t)j * plane) = make_float4(res[0], res[1], res[2], res[3]);
        }

        // rotate rows (pure renaming under full unroll — no v_movs)
        #pragma unroll
        for (int c = 0; c < Cn; ++c)
            #pragma unroll
            for (int k = 0; k < 6; ++k) {
                t[c][k] = m[c][k];
                m[c][k] = bot[c][k];
            }
    }
}

extern "C" void kernel_launch(void* const* d_in, const int* in_sizes, int n_in,
                              void* d_out, int out_size, void* d_ws, size_t ws_size,
                              hipStream_t stream) {
    const float* x   = (const float*)d_in[0];
    // d_in[1] = filters — fixed identity/sobel/laplacian stack, hardcoded above
    const float* w1w = (const float*)d_in[2];
    const float* w1b = (const float*)d_in[3];
    const float* w2w = (const float*)d_in[4];
    const float* w2b = (const float*)d_in[5];
    const float* w3w = (const float*)d_in[6];
    const float* w3b = (const float*)d_in[7];
    float* out = (float*)d_out;

    int total  = Bn * (Hn / R) * (Wn / 4);       // 262,144 threads
    int blocks = total / 256;                    // 1024 blocks
    nca_strip<<<blocks, 256, 0, stream>>>(x, w1w, w1b, w2w, w2b, w3w, w3b, out);
}

// Round 4
// 143.316 us; speedup vs baseline: 1.2894x; 1.2894x over previous
//
#include <hip/hip_runtime.h>

// Fused NCA step — wave = one full 512-px row, 8 px/lane.
// Circular pad in w handled by lane shuffles (row wraps exactly around the
// 64-lane wave). Row/base addresses are wave-uniform -> SGPR (SALU).
// Column-separable stencil: s = t+2m+b, d = b-t; then
//   sobel_x = s[+1]-s[-1]; sobel_y = d[-1]+2d+d[+1]; lap = s[-1]+2s+s[+1]-16m.
// Only acc[6][8] persists across the channel loop (register discipline:
// R2/R3 showed >128 VGPR collapses occupancy). x centers reloaded in epilogue.

constexpr int Bn = 16, Cn = 4, Hn = 512, Wn = 512, HID = 6;

__device__ __forceinline__ float frcp(float v) { return __builtin_amdgcn_rcpf(v); }

__global__ __launch_bounds__(256) void nca_row(
    const float* __restrict__ x,
    const float* __restrict__ w1w, const float* __restrict__ w1b,
    const float* __restrict__ w2w, const float* __restrict__ w2b,
    const float* __restrict__ w3w, const float* __restrict__ w3b,
    float* __restrict__ out)
{
    const int lane = threadIdx.x & 63;
    const int wv   = threadIdx.x >> 6;
    // wave-uniform row id 0..8191 — force into SGPR so row bases are scalar
    const int row = __builtin_amdgcn_readfirstlane((int)blockIdx.x * 4 + wv);
    const int h  = row & (Hn - 1);
    const int b  = row >> 9;
    const int hm = (h - 1) & (Hn - 1);
    const int hp = (h + 1) & (Hn - 1);

    const int w0 = lane << 3;                    // 8 px per lane, full row per wave
    const int laneL = (lane + 63) & 63;
    const int laneR = (lane + 1) & 63;

    const size_t plane = (size_t)Hn * Wn;
    const float* xb = x + (size_t)b * Cn * plane;

    float acc[HID][8];
    #pragma unroll
    for (int o = 0; o < HID; ++o) {
        float bv = w1b[o];
        #pragma unroll
        for (int i = 0; i < 8; ++i) acc[o][i] = bv;
    }

    #pragma unroll
    for (int c = 0; c < Cn; ++c) {
        const float* rt = xb + c * plane + (size_t)hm * Wn;   // wave-uniform bases
        const float* rm = xb + c * plane + (size_t)h  * Wn;
        const float* rb = xb + c * plane + (size_t)hp * Wn;
        float4 t0 = *(const float4*)(rt + w0), t1 = *(const float4*)(rt + w0 + 4);
        float4 m0 = *(const float4*)(rm + w0), m1 = *(const float4*)(rm + w0 + 4);
        float4 b0 = *(const float4*)(rb + w0), b1 = *(const float4*)(rb + w0 + 4);
        float t[8] = { t0.x, t0.y, t0.z, t0.w, t1.x, t1.y, t1.z, t1.w };
        float m[8] = { m0.x, m0.y, m0.z, m0.w, m1.x, m1.y, m1.z, m1.w };
        float q[8] = { b0.x, b0.y, b0.z, b0.w, b1.x, b1.y, b1.z, b1.w };

        float s[8], d[8];
        #pragma unroll
        for (int j = 0; j < 8; ++j) {
            s[j] = fmaf(2.f, m[j], t[j] + q[j]);
            d[j] = q[j] - t[j];
        }

        // circular halos via wave shuffle: wave spans the whole row, so
        // lane 0's left neighbor is lane 63 (px 511) — wrap is exact.
        float sL = __shfl(s[7], laneL), dL = __shfl(d[7], laneL);
        float sR = __shfl(s[0], laneR), dR = __shfl(d[0], laneR);

        #pragma unroll
        for (int i = 0; i < 8; ++i) {
            float sm = (i == 0) ? sL : s[i - 1];
            float sp = (i == 7) ? sR : s[i + 1];
            float dm = (i == 0) ? dL : d[i - 1];
            float dp = (i == 7) ? dR : d[i + 1];
            float mc = m[i];
            float y1 = sp - sm;                                   // sobel_x
            float y2 = fmaf(2.f, d[i], dm + dp);                  // sobel_y
            float y3 = fmaf(-16.f, mc, fmaf(2.f, s[i], sm + sp)); // laplacian
            #pragma unroll
            for (int o = 0; o < HID; ++o) {
                acc[o][i] = fmaf(w1w[o*16 + c*4 + 0], mc,
                            fmaf(w1w[o*16 + c*4 + 1], y1,
                            fmaf(w1w[o*16 + c*4 + 2], y2,
                            fmaf(w1w[o*16 + c*4 + 3], y3, acc[o][i]))));
            }
        }
    }

    #pragma unroll
    for (int o = 0; o < HID; ++o)
        #pragma unroll
        for (int i = 0; i < 8; ++i)
            acc[o][i] = fmaxf(acc[o][i], 0.f);   // relu

    // epilogue: per output channel, reload x centers (L1-hot) and blend
    float* ob = out + (size_t)b * Cn * plane + (size_t)h * Wn;
    #pragma unroll
    for (int j = 0; j < Cn; ++j) {
        const float* rc = xb + j * plane + (size_t)h * Wn;
        float4 c0 = *(const float4*)(rc + w0), c1 = *(const float4*)(rc + w0 + 4);
        float xc[8] = { c0.x, c0.y, c0.z, c0.w, c1.x, c1.y, c1.z, c1.w };
        float res[8];
        #pragma unroll
        for (int i = 0; i < 8; ++i) {
            float u = w2b[j], gg = w3b[j];
            #pragma unroll
            for (int o = 0; o < HID; ++o) {
                u  = fmaf(w2w[j*HID + o], acc[o][i], u);
                gg = fmaf(w3w[j*HID + o], acc[o][i], gg);
            }
            // tanh(u) = 1 - 2/(exp(2u)+1); sigmoid(g) = 1/(1+exp(-g))
            float th = 1.f - 2.f * frcp(__expf(2.f * u) + 1.f);
            float sg = frcp(1.f + __expf(-gg));
            res[i] = fmaf(sg, xc[i] - th, th);
        }
        *(float4*)(ob + j * plane + w0)     = make_float4(res[0], res[1], res[2], res[3]);
        *(float4*)(ob + j * plane + w0 + 4) = make_float4(res[4], res[5], res[6], res[7]);
    }
}

extern "C" void kernel_launch(void* const* d_in, const int* in_sizes, int n_in,
                              void* d_out, int out_size, void* d_ws, size_t ws_size,
                              hipStream_t stream) {
    const float* x   = (const float*)d_in[0];
    // d_in[1] = filters — fixed identity/sobel/laplacian stack, hardcoded above
    const float* w1w = (const float*)d_in[2];
    const float* w1b = (const float*)d_in[3];
    const float* w2w = (const float*)d_in[4];
    const float* w2b = (const float*)d_in[5];
    const float* w3w = (const float*)d_in[6];
    const float* w3b = (const float*)d_in[7];
    float* out = (float*)d_out;

    int rows   = Bn * Hn;                        // 8192 waves, one row each
    int blocks = rows / 4;                       // 2048 blocks of 4 waves
    nca_row<<<blocks, 256, 0, stream>>>(x, w1w, w1b, w2w, w2b, w3w, w3b, out);
}